// Round 8
// baseline (321.392 us; speedup 1.0000x reference)
//
#include <hip/hip_runtime.h>
#include <math.h>

#define NUM_EMB 1024
#define EMB_DIM 256
#define N_ROWS  65536
#define HW      1024
#define QUANT_OFF 1
#define IDX_OFF   (1 + 16777216)
#define LDA 264   // halfs per A-row: 528B stride -> clean b128 access, 2-way banks (free)
#define KSTR 132  // key-scratch row stride in dwords

typedef unsigned int uint;
typedef _Float16 f16x8 __attribute__((ext_vector_type(8)));
typedef float    f32x4 __attribute__((ext_vector_type(4)));

__device__ __forceinline__ uint umin2(uint a, uint b) { return a < b ? a : b; }
__device__ __forceinline__ uint umax2(uint a, uint b) { return a > b ? a : b; }

// median of 3 == 2nd-largest of 3; single VALU op on gfx9+
__device__ __forceinline__ uint umed3(uint a, uint b, uint c) {
  uint d;
  asm("v_med3_u32 %0, %1, %2, %3" : "=v"(d) : "v"(a), "v"(b), "v"(c));
  return d;
}

// ---- kernel 1: normalize codebook -> wn (f32), wh2 (f16, MFMA-B-swizzled), rinv (f64) ----
// wh2 halfs layout: [chunk(4)][ks(8)][q(4)][code-in-chunk(256)][e(8)], d = ks*32+q*8+e.
// Equivalently: slab s = chunk*8+ks at offset s*8192.
__global__ __launch_bounds__(256)
void k_norm_w(const float* __restrict__ w, float* __restrict__ wn,
              _Float16* __restrict__ wh2, double* __restrict__ rinv) {
  const int k = blockIdx.x, t = threadIdx.x;
  const float v = w[(size_t)k * EMB_DIM + t];
  double s = (double)v * (double)v;
  for (int o = 32; o; o >>= 1) s += __shfl_down(s, o);
  __shared__ double ps[4];
  if ((t & 63) == 0) ps[t >> 6] = s;
  __syncthreads();
  const double tot = ps[0] + ps[1] + ps[2] + ps[3];
  const float nv = v / fmaxf((float)sqrt(tot), 1e-12f);
  wn[(size_t)k * EMB_DIM + t] = nv;
  const int chunk = k >> 8, cc = k & 255;
  const int ks = t >> 5, q = (t >> 3) & 3, e = t & 7;
  wh2[(size_t)chunk * 65536 + ks * 8192 + q * 2048 + cc * 8 + e] = (_Float16)nv;
  if (t == 0) rinv[k] = 1.0 / fmax(sqrt(tot), 1e-12);
}

// ---- fused kernel: 64-row MFMA top-4 + fp64 recheck + loss + quant ----
// 1024 blocks x 256 thr, 64 rows/block (512 MB B L2 traffic).
// B streamed L2->VGPR, DEPTH-2 prefetch via 4 NAMED buffers (period-4, all static
// names -- no dynamic ext_vector indexing, rule #20). ~200 VGPR under (256,2):
// 2 blocks/CU resident, 4 queued -> phase-skew rotation.
// Recheck re-reads x (L3-hit); quant stores direct coalesced.
__global__ __launch_bounds__(256, 2)
void k_fused(const float* __restrict__ x, const _Float16* __restrict__ wh2,
             const float* __restrict__ w, const float* __restrict__ wn,
             const double* __restrict__ rinv, float* __restrict__ out) {
  __shared__ __align__(16) _Float16 As[64 * LDA];   // 33792 B; reused: keys / red
  __shared__ uint4 cand_s[64];
  __shared__ int   cw_s[64];
  const int t = threadIdx.x;
  const int blk = blockIdx.x;
  const int b = blk >> 4;
  const int hw0 = (blk & 15) * 64;

  const int lane = t & 63;
  const int q = lane >> 4;
  const int l15 = lane & 15;
  const int w4id = t >> 6;

  // per-lane B element offsets (halfs) within a ks-slab of wh2
  const int bvo0 = q * 2048 + (w4id * 64 +  0 + l15) * 8;
  const int bvo1 = q * 2048 + (w4id * 64 + 16 + l15) * 8;
  const int bvo2 = q * 2048 + (w4id * 64 + 32 + l15) * 8;
  const int bvo3 = q * 2048 + (w4id * 64 + 48 + l15) * 8;

#define LOADB(buf, s)                                       \
  { const _Float16* ksb_ = wh2 + (size_t)(s) * 8192;        \
    buf[0] = *(const f16x8*)&ksb_[bvo0];                    \
    buf[1] = *(const f16x8*)&ksb_[bvo1];                    \
    buf[2] = *(const f16x8*)&ksb_[bvo2];                    \
    buf[3] = *(const f16x8*)&ksb_[bvo3]; }

  // 4 named B buffers: step s consumes phase s%4, prefetches s+2 into (s+2)%4.
  f16x8 bA[4], bB[4], bC[4], bD[4];
  LOADB(bA, 0);   // s=0
  LOADB(bB, 1);   // s=1   (both overlap A staging)

  // stage A: x[b, d, hw0+r] f32 -> As[r][d] f16, packed 8 halfs per ds_write_b128
  const int r_own = t & 63;   // row this thread owns (staging, recheck, quant)
  const int ph = t >> 6;      // d-slice: ph*64 .. ph*64+63
  {
    const float* xb = x + (size_t)b * (EMB_DIM * HW) + hw0 + r_own;
#pragma unroll
    for (int jp = 0; jp < 8; ++jp) {
      const int d0 = ph * 64 + jp * 8;
      f16x8 v;
#pragma unroll
      for (int e = 0; e < 8; ++e)
        v[e] = (_Float16)xb[(size_t)(d0 + e) * HW];
      *(f16x8*)&As[r_own * LDA + d0] = v;
    }
  }
  __syncthreads();   // A tile staged

  uint t1[16], t2[16];
#pragma unroll
  for (int i = 0; i < 16; ++i) { t1[i] = 0u; t2[i] = 0u; }

  // one K-step: prefetch s+2 into PREB, ds_read 4 A-frags at ksv, 16 MFMAs on CURB
#define MMSTEP(c4v, ksv, CURB, PREB)                                                   \
  { const int sp_ = (c4v) * 8 + (ksv) + 2;                                             \
    if (sp_ < 32) { LOADB(PREB, sp_); }                                                \
    const f16x8 a0 = *(const f16x8*)&As[( 0 + l15) * LDA + (ksv) * 32 + q * 8];        \
    const f16x8 a1 = *(const f16x8*)&As[(16 + l15) * LDA + (ksv) * 32 + q * 8];        \
    const f16x8 a2 = *(const f16x8*)&As[(32 + l15) * LDA + (ksv) * 32 + q * 8];        \
    const f16x8 a3 = *(const f16x8*)&As[(48 + l15) * LDA + (ksv) * 32 + q * 8];        \
    __builtin_amdgcn_s_setprio(1);                                                     \
    _Pragma("unroll")                                                                  \
    for (int ct = 0; ct < 4; ++ct) {                                                   \
      acc[0][ct] = __builtin_amdgcn_mfma_f32_16x16x32_f16(a0, CURB[ct], acc[0][ct], 0, 0, 0); \
      acc[1][ct] = __builtin_amdgcn_mfma_f32_16x16x32_f16(a1, CURB[ct], acc[1][ct], 0, 0, 0); \
      acc[2][ct] = __builtin_amdgcn_mfma_f32_16x16x32_f16(a2, CURB[ct], acc[2][ct], 0, 0, 0); \
      acc[3][ct] = __builtin_amdgcn_mfma_f32_16x16x32_f16(a3, CURB[ct], acc[3][ct], 0, 0, 0); \
    }                                                                                  \
    __builtin_amdgcn_s_setprio(0); }

#pragma unroll 1
  for (int c4 = 0; c4 < 4; ++c4) {
    f32x4 acc[4][4];
#pragma unroll
    for (int rt = 0; rt < 4; ++rt)
#pragma unroll
      for (int ct = 0; ct < 4; ++ct) acc[rt][ct] = (f32x4)0.f;

    // 8 K-steps; buffer phase pattern repeats every 4 (8 % 4 == 0 -> same per chunk)
    MMSTEP(c4, 0, bA, bC);
    MMSTEP(c4, 1, bB, bD);
    MMSTEP(c4, 2, bC, bA);
    MMSTEP(c4, 3, bD, bB);
    MMSTEP(c4, 4, bA, bC);
    MMSTEP(c4, 5, bB, bD);
    MMSTEP(c4, 6, bC, bA);
    MMSTEP(c4, 7, bD, bB);

    // merge into per-(lane,slot) top-2 packed keys (score hi-bits | idx);
    // overlaps the in-flight prefetches for the next chunk
#pragma unroll
    for (int ct = 0; ct < 4; ++ct) {
      const uint idxv = (uint)(c4 * 256 + w4id * 64 + ct * 16 + l15);
#pragma unroll
      for (int rt = 0; rt < 4; ++rt)
#pragma unroll
        for (int r = 0; r < 4; ++r) {
          const float v = fmaxf(acc[rt][ct][r], 0.0f);
          const uint key = (__float_as_uint(v) & 0xFFFFFC00u) | idxv;
          const int slot = rt * 4 + r;
          t2[slot] = umed3(key, t1[slot], t2[slot]);
          t1[slot] = umax2(key, t1[slot]);
        }
    }
  }
#undef MMSTEP
#undef LOADB

  // ---- block-level per-row top-4 (reuse A LDS as key scratch: 64 rows x KSTR dwords) ----
  __syncthreads();   // all waves done reading As
  uint* keys = (uint*)As;
#pragma unroll
  for (int slot = 0; slot < 16; ++slot) {
    const int rt = slot >> 2, r = slot & 3;
    const int row = rt * 16 + q * 4 + r;
    const int col = w4id * 32 + l15 * 2;
    keys[row * KSTR + col] = t1[slot];
    keys[row * KSTR + col + 1] = t2[slot];
  }
  __syncthreads();
  {
    const int row = t >> 2, seg = t & 3;   // 4 threads per row, 32 keys each
    uint s1 = 0, s2 = 0;
#pragma unroll
    for (int i = 0; i < 8; ++i) {
      const int ii = (i + t) & 7;
      const uint4 k4 = *(const uint4*)&keys[row * KSTR + seg * 32 + ii * 4];
      const uint kk[4] = {k4.x, k4.y, k4.z, k4.w};
#pragma unroll
      for (int e = 0; e < 4; ++e) {
        s2 = umed3(kk[e], s1, s2);
        s1 = umax2(kk[e], s1);
      }
    }
    __syncthreads();
    keys[t * 2] = s1;
    keys[t * 2 + 1] = s2;
  }
  __syncthreads();
  if (t < 64) {
    uint c0 = 0, c1 = 0, c2 = 0, c3 = 0;
#pragma unroll
    for (int i = 0; i < 8; ++i) {
      const uint k = keys[t * 8 + i];
      const uint n0 = umin2(c0, k); c0 = umax2(c0, k);
      const uint n1 = umin2(c1, n0); c1 = umax2(c1, n0);
      const uint n2 = umin2(c2, n1); c2 = umax2(c2, n1);
      c3 = umax2(c3, n2);
    }
    uint4 o; o.x = c0; o.y = c1; o.z = c2; o.w = c3;
    cand_s[t] = o;
  }
  __syncthreads();   // cand ready; keys region free for red reuse

  // ---- fp64 recheck: thread covers (r_own, 64-d slice); x re-read (L3-hit) ----
  double* red = (double*)As;   // 256 threads x 5 doubles = 10240 B
  {
    const uint4 ck = cand_s[r_own];
    const uint cv[4] = {ck.x, ck.y, ck.z, ck.w};
    const float* xr = x + (size_t)b * (EMB_DIM * HW) + hw0 + r_own;
    float xf[64];
#pragma unroll
    for (int i = 0; i < 64; ++i)
      xf[i] = xr[(size_t)(ph * 64 + i) * HW];
    double sxx_p = 0.0;
#pragma unroll
    for (int i = 0; i < 64; ++i) sxx_p = fma((double)xf[i], (double)xf[i], sxx_p);
#pragma unroll
    for (int j = 0; j < 4; ++j) {
      const int c = (int)(cv[j] & 1023u);
      const float* wr = w + (size_t)c * EMB_DIM + ph * 64;
      double s = 0.0;
#pragma unroll
      for (int k = 0; k < 16; ++k) {
        const float4 wv = *(const float4*)&wr[k * 4];
        s = fma((double)xf[k * 4 + 0], (double)wv.x, s);
        s = fma((double)xf[k * 4 + 1], (double)wv.y, s);
        s = fma((double)xf[k * 4 + 2], (double)wv.z, s);
        s = fma((double)xf[k * 4 + 3], (double)wv.w, s);
      }
      red[t * 5 + j] = s;
    }
    red[t * 5 + 4] = sxx_p;
  }
  __syncthreads();

  // ---- per-row decision (first 64 lanes), loss reduce, idx store ----
  if (t < 64) {
    const uint4 ck = cand_s[t];
    const uint cv[4] = {ck.x, ck.y, ck.z, ck.w};
    double sj[4] = {0.0, 0.0, 0.0, 0.0};
    double sxx = 0.0;
#pragma unroll
    for (int p = 0; p < 4; ++p) {
      const int base = (p * 64 + t) * 5;
      sj[0] += red[base + 0];
      sj[1] += red[base + 1];
      sj[2] += red[base + 2];
      sj[3] += red[base + 3];
      sxx   += red[base + 4];
    }
    double qbest = -1e300; int cw = 1 << 30;
#pragma unroll
    for (int j = 0; j < 4; ++j) {
      const int c = (int)(cv[j] & 1023u);
      const double qj = sj[j] * rinv[c];
      if (qj > qbest || (qj == qbest && c < cw)) { qbest = qj; cw = c; }
    }
    const double dmin = 2.0 - 2.0 * qbest / fmax(sqrt(sxx), 1e-12);
    out[IDX_OFF + blk * 64 + t] = (float)cw;
    cw_s[t] = cw;
    double v = dmin;
    v += __shfl_down(v, 32);
    v += __shfl_down(v, 16);
    v += __shfl_down(v, 8);
    v += __shfl_down(v, 4);
    v += __shfl_down(v, 2);
    v += __shfl_down(v, 1);
    if (t == 0)
      atomicAdd(out, (float)(1.25 * v / 16777216.0));
  }
  __syncthreads();

  // ---- quant: direct coalesced stores (wave-per-64-rows, 256B segments per d) ----
  {
    const int cw = cw_s[r_own];
    const float* wr = wn + (size_t)cw * EMB_DIM + ph * 64;
    float* qo = out + QUANT_OFF + (size_t)b * (EMB_DIM * HW) + hw0 + r_own;
#pragma unroll
    for (int k = 0; k < 16; ++k) {
      const float4 wv = *(const float4*)&wr[k * 4];
      qo[(size_t)(ph * 64 + k * 4 + 0) * HW] = wv.x;
      qo[(size_t)(ph * 64 + k * 4 + 1) * HW] = wv.y;
      qo[(size_t)(ph * 64 + k * 4 + 2) * HW] = wv.z;
      qo[(size_t)(ph * 64 + k * 4 + 3) * HW] = wv.w;
    }
  }
}

extern "C" void kernel_launch(void* const* d_in, const int* in_sizes, int n_in,
                              void* d_out, int out_size, void* d_ws, size_t ws_size,
                              hipStream_t stream) {
  const float* x = (const float*)d_in[0];   // [64,256,32,32]
  const float* w = (const float*)d_in[1];   // [1024,256]
  float* out = (float*)d_out;               // [1 + 16777216 + 65536] f32

  char* ws = (char*)d_ws;
  float*     wn   = (float*)ws;                                // 1 MB
  _Float16*  wh2  = (_Float16*)(ws + 1048576);                 // 512 KB (swizzled)
  double*    rinv = (double*)(ws + 1048576 + 524288);          // 8 KB

  hipMemsetAsync(d_out, 0, sizeof(float), stream);   // zero loss accumulator
  hipLaunchKernelGGL(k_norm_w, dim3(NUM_EMB), dim3(256), 0, stream, w, wn, wh2, rinv);
  hipLaunchKernelGGL(k_fused, dim3(N_ROWS / 64), dim3(256), 0, stream, x, wh2, w, wn, rinv, out);
}

// Round 9
// 294.606 us; speedup vs baseline: 1.0909x; 1.0909x over previous
//
#include <hip/hip_runtime.h>
#include <math.h>

#define NUM_EMB 1024
#define EMB_DIM 256
#define N_ROWS  65536
#define HW      1024
#define QUANT_OFF 1
#define IDX_OFF   (1 + 16777216)
#define LDA 264   // halfs per A-row: 528B stride -> clean b128 access, 2-way banks (free)
#define KSTR 132  // key-scratch row stride in dwords

typedef unsigned int uint;
typedef _Float16 f16x8 __attribute__((ext_vector_type(8)));
typedef float    f32x4 __attribute__((ext_vector_type(4)));

__device__ __forceinline__ uint umin2(uint a, uint b) { return a < b ? a : b; }
__device__ __forceinline__ uint umax2(uint a, uint b) { return a > b ? a : b; }

// median of 3 == 2nd-largest of 3; single VALU op on gfx9+
__device__ __forceinline__ uint umed3(uint a, uint b, uint c) {
  uint d;
  asm("v_med3_u32 %0, %1, %2, %3" : "=v"(d) : "v"(a), "v"(b), "v"(c));
  return d;
}

// ---- kernel 1: normalize codebook -> wn (f32), wh2 (f16, MFMA-B-swizzled), rinv (f64) ----
// wh2 halfs layout: [chunk(4)][ks(8)][q(4)][code-in-chunk(256)][e(8)], d = ks*32+q*8+e.
// Equivalently: slab s = chunk*8+ks at offset s*8192.
__global__ __launch_bounds__(256)
void k_norm_w(const float* __restrict__ w, float* __restrict__ wn,
              _Float16* __restrict__ wh2, double* __restrict__ rinv) {
  const int k = blockIdx.x, t = threadIdx.x;
  const float v = w[(size_t)k * EMB_DIM + t];
  double s = (double)v * (double)v;
  for (int o = 32; o; o >>= 1) s += __shfl_down(s, o);
  __shared__ double ps[4];
  if ((t & 63) == 0) ps[t >> 6] = s;
  __syncthreads();
  const double tot = ps[0] + ps[1] + ps[2] + ps[3];
  const float nv = v / fmaxf((float)sqrt(tot), 1e-12f);
  wn[(size_t)k * EMB_DIM + t] = nv;
  const int chunk = k >> 8, cc = k & 255;
  const int ks = t >> 5, q = (t >> 3) & 3, e = t & 7;
  wh2[(size_t)chunk * 65536 + ks * 8192 + q * 2048 + cc * 8 + e] = (_Float16)nv;
  if (t == 0) rinv[k] = 1.0 / fmax(sqrt(tot), 1e-12);
}

// ---- fused kernel: 64-row MFMA top-4 + fp64 recheck + loss + quant ----
// 1024 blocks x 256 thr, 64 rows/block. GEMM = round-3's proven loop (depth-1
// bb[2][4], acc[4][4]: 84 VGPR + 64 AGPR = 148 total -> 3 waves/SIMD under (256,3)).
// NO state held across phases (round-4's xv[64] cost the 3rd wave/SIMD: 180 regs
// -> 2 waves/SIMD -> 96us). Recheck re-reads x (L3-hit); quant stores direct.
__global__ __launch_bounds__(256, 3)
void k_fused(const float* __restrict__ x, const _Float16* __restrict__ wh2,
             const float* __restrict__ w, const float* __restrict__ wn,
             const double* __restrict__ rinv, float* __restrict__ out) {
  __shared__ __align__(16) _Float16 As[64 * LDA];   // 33792 B; reused: keys / red
  __shared__ uint4 cand_s[64];
  __shared__ int   cw_s[64];
  const int t = threadIdx.x;
  const int blk = blockIdx.x;
  const int b = blk >> 4;
  const int hw0 = (blk & 15) * 64;

  const int lane = t & 63;
  const int q = lane >> 4;
  const int l15 = lane & 15;
  const int w4id = t >> 6;

  // per-lane B element offsets (halfs) within a ks-slab of wh2
  const int bvo0 = q * 2048 + (w4id * 64 +  0 + l15) * 8;
  const int bvo1 = q * 2048 + (w4id * 64 + 16 + l15) * 8;
  const int bvo2 = q * 2048 + (w4id * 64 + 32 + l15) * 8;
  const int bvo3 = q * 2048 + (w4id * 64 + 48 + l15) * 8;

#define LOADB(buf, s)                                       \
  { const _Float16* ksb_ = wh2 + (size_t)(s) * 8192;        \
    buf[0] = *(const f16x8*)&ksb_[bvo0];                    \
    buf[1] = *(const f16x8*)&ksb_[bvo1];                    \
    buf[2] = *(const f16x8*)&ksb_[bvo2];                    \
    buf[3] = *(const f16x8*)&ksb_[bvo3]; }

  f16x8 bb[2][4];
  LOADB(bb[0], 0);   // prefetch first B step (overlaps A staging)

  // stage A: x[b, d, hw0+r] f32 -> As[r][d] f16, packed 8 halfs per ds_write_b128
  const int r_own = t & 63;   // row this thread owns (staging, recheck, quant)
  const int ph = t >> 6;      // d-slice: ph*64 .. ph*64+63
  {
    const float* xb = x + (size_t)b * (EMB_DIM * HW) + hw0 + r_own;
#pragma unroll
    for (int jp = 0; jp < 8; ++jp) {
      const int d0 = ph * 64 + jp * 8;
      f16x8 v;
#pragma unroll
      for (int e = 0; e < 8; ++e)
        v[e] = (_Float16)xb[(size_t)(d0 + e) * HW];
      *(f16x8*)&As[r_own * LDA + d0] = v;
    }
  }
  __syncthreads();   // A tile staged

  uint t1[16], t2[16];
#pragma unroll
  for (int i = 0; i < 16; ++i) { t1[i] = 0u; t2[i] = 0u; }

#pragma unroll
  for (int c4 = 0; c4 < 4; ++c4) {
    f32x4 acc[4][4];
#pragma unroll
    for (int rt = 0; rt < 4; ++rt)
#pragma unroll
      for (int ct = 0; ct < 4; ++ct) acc[rt][ct] = (f32x4)0.f;

#pragma unroll
    for (int ks = 0; ks < 8; ++ks) {
      const int s = c4 * 8 + ks;          // compile-time after unroll
      const int cb = s & 1, nb = cb ^ 1;  // STATIC double-buffer indices
      if (s < 31) { LOADB(bb[nb], s + 1); }   // depth-1 prefetch, linear slabs

      const f16x8 a0 = *(const f16x8*)&As[( 0 + l15) * LDA + ks * 32 + q * 8];
      const f16x8 a1 = *(const f16x8*)&As[(16 + l15) * LDA + ks * 32 + q * 8];
      const f16x8 a2 = *(const f16x8*)&As[(32 + l15) * LDA + ks * 32 + q * 8];
      const f16x8 a3 = *(const f16x8*)&As[(48 + l15) * LDA + ks * 32 + q * 8];

      __builtin_amdgcn_s_setprio(1);
#pragma unroll
      for (int ct = 0; ct < 4; ++ct) {
        acc[0][ct] = __builtin_amdgcn_mfma_f32_16x16x32_f16(a0, bb[cb][ct], acc[0][ct], 0, 0, 0);
        acc[1][ct] = __builtin_amdgcn_mfma_f32_16x16x32_f16(a1, bb[cb][ct], acc[1][ct], 0, 0, 0);
        acc[2][ct] = __builtin_amdgcn_mfma_f32_16x16x32_f16(a2, bb[cb][ct], acc[2][ct], 0, 0, 0);
        acc[3][ct] = __builtin_amdgcn_mfma_f32_16x16x32_f16(a3, bb[cb][ct], acc[3][ct], 0, 0, 0);
      }
      __builtin_amdgcn_s_setprio(0);
    }

    // merge into per-(lane,slot) top-2 packed keys (score hi-bits | idx)
#pragma unroll
    for (int ct = 0; ct < 4; ++ct) {
      const uint idxv = (uint)(c4 * 256 + w4id * 64 + ct * 16 + l15);
#pragma unroll
      for (int rt = 0; rt < 4; ++rt)
#pragma unroll
        for (int r = 0; r < 4; ++r) {
          const float v = fmaxf(acc[rt][ct][r], 0.0f);
          const uint key = (__float_as_uint(v) & 0xFFFFFC00u) | idxv;
          const int slot = rt * 4 + r;
          t2[slot] = umed3(key, t1[slot], t2[slot]);
          t1[slot] = umax2(key, t1[slot]);
        }
    }
  }
#undef LOADB

  // ---- block-level per-row top-4 (reuse A LDS as key scratch: 64 rows x KSTR dwords) ----
  __syncthreads();   // all waves done reading As
  uint* keys = (uint*)As;
#pragma unroll
  for (int slot = 0; slot < 16; ++slot) {
    const int rt = slot >> 2, r = slot & 3;
    const int row = rt * 16 + q * 4 + r;
    const int col = w4id * 32 + l15 * 2;
    keys[row * KSTR + col] = t1[slot];
    keys[row * KSTR + col + 1] = t2[slot];
  }
  __syncthreads();
  {
    const int row = t >> 2, seg = t & 3;   // 4 threads per row, 32 keys each
    uint s1 = 0, s2 = 0;
#pragma unroll
    for (int i = 0; i < 8; ++i) {
      const int ii = (i + t) & 7;
      const uint4 k4 = *(const uint4*)&keys[row * KSTR + seg * 32 + ii * 4];
      const uint kk[4] = {k4.x, k4.y, k4.z, k4.w};
#pragma unroll
      for (int e = 0; e < 4; ++e) {
        s2 = umed3(kk[e], s1, s2);
        s1 = umax2(kk[e], s1);
      }
    }
    __syncthreads();
    keys[t * 2] = s1;
    keys[t * 2 + 1] = s2;
  }
  __syncthreads();
  if (t < 64) {
    uint c0 = 0, c1 = 0, c2 = 0, c3 = 0;
#pragma unroll
    for (int i = 0; i < 8; ++i) {
      const uint k = keys[t * 8 + i];
      const uint n0 = umin2(c0, k); c0 = umax2(c0, k);
      const uint n1 = umin2(c1, n0); c1 = umax2(c1, n0);
      const uint n2 = umin2(c2, n1); c2 = umax2(c2, n1);
      c3 = umax2(c3, n2);
    }
    uint4 o; o.x = c0; o.y = c1; o.z = c2; o.w = c3;
    cand_s[t] = o;
  }
  __syncthreads();   // cand ready; keys region free for red reuse

  // ---- fp64 recheck: thread covers (r_own, 64-d slice); x re-read (L3-hit) ----
  double* red = (double*)As;   // 256 threads x 5 doubles = 10240 B
  {
    const uint4 ck = cand_s[r_own];
    const uint cv[4] = {ck.x, ck.y, ck.z, ck.w};
    const float* xr = x + (size_t)b * (EMB_DIM * HW) + hw0 + r_own;
    float xf[64];
#pragma unroll
    for (int i = 0; i < 64; ++i)
      xf[i] = xr[(size_t)(ph * 64 + i) * HW];
    double sxx_p = 0.0;
#pragma unroll
    for (int i = 0; i < 64; ++i) sxx_p = fma((double)xf[i], (double)xf[i], sxx_p);
#pragma unroll
    for (int j = 0; j < 4; ++j) {
      const int c = (int)(cv[j] & 1023u);
      const float* wr = w + (size_t)c * EMB_DIM + ph * 64;
      double s = 0.0;
#pragma unroll
      for (int k = 0; k < 16; ++k) {
        const float4 wv = *(const float4*)&wr[k * 4];
        s = fma((double)xf[k * 4 + 0], (double)wv.x, s);
        s = fma((double)xf[k * 4 + 1], (double)wv.y, s);
        s = fma((double)xf[k * 4 + 2], (double)wv.z, s);
        s = fma((double)xf[k * 4 + 3], (double)wv.w, s);
      }
      red[t * 5 + j] = s;
    }
    red[t * 5 + 4] = sxx_p;
  }
  __syncthreads();

  // ---- per-row decision (first 64 lanes), loss reduce, idx store ----
  if (t < 64) {
    const uint4 ck = cand_s[t];
    const uint cv[4] = {ck.x, ck.y, ck.z, ck.w};
    double sj[4] = {0.0, 0.0, 0.0, 0.0};
    double sxx = 0.0;
#pragma unroll
    for (int p = 0; p < 4; ++p) {
      const int base = (p * 64 + t) * 5;
      sj[0] += red[base + 0];
      sj[1] += red[base + 1];
      sj[2] += red[base + 2];
      sj[3] += red[base + 3];
      sxx   += red[base + 4];
    }
    double qbest = -1e300; int cw = 1 << 30;
#pragma unroll
    for (int j = 0; j < 4; ++j) {
      const int c = (int)(cv[j] & 1023u);
      const double qj = sj[j] * rinv[c];
      if (qj > qbest || (qj == qbest && c < cw)) { qbest = qj; cw = c; }
    }
    const double dmin = 2.0 - 2.0 * qbest / fmax(sqrt(sxx), 1e-12);
    out[IDX_OFF + blk * 64 + t] = (float)cw;
    cw_s[t] = cw;
    double v = dmin;
    v += __shfl_down(v, 32);
    v += __shfl_down(v, 16);
    v += __shfl_down(v, 8);
    v += __shfl_down(v, 4);
    v += __shfl_down(v, 2);
    v += __shfl_down(v, 1);
    if (t == 0)
      atomicAdd(out, (float)(1.25 * v / 16777216.0));
  }
  __syncthreads();

  // ---- quant: direct coalesced stores (wave covers 64 consecutive hw per d) ----
  {
    const int cw = cw_s[r_own];
    const float* wr = wn + (size_t)cw * EMB_DIM + ph * 64;
    float* qo = out + QUANT_OFF + (size_t)b * (EMB_DIM * HW) + hw0 + r_own;
#pragma unroll
    for (int k = 0; k < 16; ++k) {
      const float4 wv = *(const float4*)&wr[k * 4];
      qo[(size_t)(ph * 64 + k * 4 + 0) * HW] = wv.x;
      qo[(size_t)(ph * 64 + k * 4 + 1) * HW] = wv.y;
      qo[(size_t)(ph * 64 + k * 4 + 2) * HW] = wv.z;
      qo[(size_t)(ph * 64 + k * 4 + 3) * HW] = wv.w;
    }
  }
}

extern "C" void kernel_launch(void* const* d_in, const int* in_sizes, int n_in,
                              void* d_out, int out_size, void* d_ws, size_t ws_size,
                              hipStream_t stream) {
  const float* x = (const float*)d_in[0];   // [64,256,32,32]
  const float* w = (const float*)d_in[1];   // [1024,256]
  float* out = (float*)d_out;               // [1 + 16777216 + 65536] f32

  char* ws = (char*)d_ws;
  float*     wn   = (float*)ws;                                // 1 MB
  _Float16*  wh2  = (_Float16*)(ws + 1048576);                 // 512 KB (swizzled)
  double*    rinv = (double*)(ws + 1048576 + 524288);          // 8 KB

  hipMemsetAsync(d_out, 0, sizeof(float), stream);   // zero loss accumulator
  hipLaunchKernelGGL(k_norm_w, dim3(NUM_EMB), dim3(256), 0, stream, w, wn, wh2, rinv);
  hipLaunchKernelGGL(k_fused, dim3(N_ROWS / 64), dim3(256), 0, stream, x, wh2, w, wn, rinv, out);
}

// Round 10
// 276.804 us; speedup vs baseline: 1.1611x; 1.0643x over previous
//
#include <hip/hip_runtime.h>
#include <math.h>

#define NUM_EMB 1024
#define EMB_DIM 256
#define N_ROWS  65536
#define HW      1024
#define QUANT_OFF 1
#define IDX_OFF   (1 + 16777216)
#define LDA 264   // halfs per A-row (256 data + 8 pad); slot-XOR swizzle breaks bank aliasing
#define KSTR 132  // key-scratch row stride in dwords

typedef unsigned int uint;
typedef _Float16 f16x8 __attribute__((ext_vector_type(8)));
typedef float    f32x4 __attribute__((ext_vector_type(4)));

// A-tile 16B-slot swizzle: row's slot s (0..31) stored at s ^ ((row&7)<<2).
// Spreads the 8-row stripe across all 32 banks for both ds_write_b128 (stage)
// and ds_read_b128 (GEMM a-frags); residual aliasing is the free 2-way.
#define SWZ(row, slot) ((slot) ^ (((row) & 7) << 2))

__device__ __forceinline__ uint umin2(uint a, uint b) { return a < b ? a : b; }
__device__ __forceinline__ uint umax2(uint a, uint b) { return a > b ? a : b; }

// median of 3 == 2nd-largest of 3; single VALU op on gfx9+
__device__ __forceinline__ uint umed3(uint a, uint b, uint c) {
  uint d;
  asm("v_med3_u32 %0, %1, %2, %3" : "=v"(d) : "v"(a), "v"(b), "v"(c));
  return d;
}

// ---- kernel 1: normalize codebook -> wn (f32), wh2 (f16, MFMA-B-swizzled), rinv (f64) ----
// wh2 halfs layout: [chunk(4)][ks(8)][q(4)][code-in-chunk(256)][e(8)], d = ks*32+q*8+e.
__global__ __launch_bounds__(256)
void k_norm_w(const float* __restrict__ w, float* __restrict__ wn,
              _Float16* __restrict__ wh2, double* __restrict__ rinv) {
  const int k = blockIdx.x, t = threadIdx.x;
  const float v = w[(size_t)k * EMB_DIM + t];
  double s = (double)v * (double)v;
  for (int o = 32; o; o >>= 1) s += __shfl_down(s, o);
  __shared__ double ps[4];
  if ((t & 63) == 0) ps[t >> 6] = s;
  __syncthreads();
  const double tot = ps[0] + ps[1] + ps[2] + ps[3];
  const float nv = v / fmaxf((float)sqrt(tot), 1e-12f);
  wn[(size_t)k * EMB_DIM + t] = nv;
  const int chunk = k >> 8, cc = k & 255;
  const int ks = t >> 5, q = (t >> 3) & 3, e = t & 7;
  wh2[(size_t)chunk * 65536 + ks * 8192 + q * 2048 + cc * 8 + e] = (_Float16)nv;
  if (t == 0) rinv[k] = 1.0 / fmax(sqrt(tot), 1e-12);
}

// ---- fused kernel (round-4 structure, proven 96us): MFMA top-4 + fp64 recheck + loss + quant ----
// 1024 blocks x 256 thr, 64 rows/block. x row-slice kept in f32 registers (xv[64])
// through the MFMA phase (116 VGPR + 64 AGPR under (256,2), no spill); recheck uses
// xv (zero reloads); quant via two 32-row transpose passes reusing the As LDS buffer.
// Changes vs r4: As slot-XOR swizzle (bank conflicts 2.3M -> ~0); setprio removed (m190).
__global__ __launch_bounds__(256, 2)
void k_fused(const float* __restrict__ x, const _Float16* __restrict__ wh2,
             const float* __restrict__ w, const float* __restrict__ wn,
             const double* __restrict__ rinv, float* __restrict__ out) {
  __shared__ __align__(16) _Float16 As[64 * LDA];   // 33792 B; reused: keys / red / qs
  __shared__ uint4 cand_s[64];
  __shared__ int   cw_s[64];
  const int t = threadIdx.x;
  const int blk = blockIdx.x;
  const int b = blk >> 4;
  const int hw0 = (blk & 15) * 64;

  const int lane = t & 63;
  const int q = lane >> 4;
  const int l15 = lane & 15;
  const int w4id = t >> 6;

  // per-lane B element offsets (halfs) within a ks-slab of wh2
  const int bvo0 = q * 2048 + (w4id * 64 +  0 + l15) * 8;
  const int bvo1 = q * 2048 + (w4id * 64 + 16 + l15) * 8;
  const int bvo2 = q * 2048 + (w4id * 64 + 32 + l15) * 8;
  const int bvo3 = q * 2048 + (w4id * 64 + 48 + l15) * 8;

#define LOADB(buf, cc, kk)                                            \
  { const _Float16* ksb_ = wh2 + (size_t)((cc) * 8 + (kk)) * 8192;    \
    buf[0] = *(const f16x8*)&ksb_[bvo0];                              \
    buf[1] = *(const f16x8*)&ksb_[bvo1];                              \
    buf[2] = *(const f16x8*)&ksb_[bvo2];                              \
    buf[3] = *(const f16x8*)&ksb_[bvo3]; }

  f16x8 bb[2][4];
  LOADB(bb[0], 0, 0);   // prefetch first B step (overlaps A staging)

  // stage A: x[b, d, hw0+r] f32 -> As[r][swz(slot)] f16; KEEP the f32 values in registers
  const int r_own = t & 63;       // row this thread owns for staging & recheck
  const int ph = t >> 6;          // d-range: ph*64 .. ph*64+63
  float xv[64];
  {
    const float* xb = x + (size_t)b * (EMB_DIM * HW) + hw0 + r_own;
#pragma unroll
    for (int jp = 0; jp < 8; ++jp) {
      const int d0 = ph * 64 + jp * 8;
      f16x8 v;
#pragma unroll
      for (int e = 0; e < 8; ++e) {
        const float f = xb[(size_t)(d0 + e) * HW];
        xv[jp * 8 + e] = f;
        v[e] = (_Float16)f;
      }
      *(f16x8*)&As[r_own * LDA + SWZ(r_own, d0 >> 3) * 8] = v;
    }
  }
  __syncthreads();   // A tile staged

  uint t1[16], t2[16];
#pragma unroll
  for (int i = 0; i < 16; ++i) { t1[i] = 0u; t2[i] = 0u; }

#pragma unroll
  for (int c4 = 0; c4 < 4; ++c4) {
    f32x4 acc[4][4];
#pragma unroll
    for (int rt = 0; rt < 4; ++rt)
#pragma unroll
      for (int ct = 0; ct < 4; ++ct) acc[rt][ct] = (f32x4)0.f;

#pragma unroll
    for (int ks = 0; ks < 8; ++ks) {
      const int s = c4 * 8 + ks;
      const int cb = s & 1, nb = cb ^ 1;
      if (s < 31) {
        const int sn = s + 1;
        LOADB(bb[nb], sn >> 3, sn & 7);
      }

      const int slot = ks * 4 + q;
      const f16x8 a0 = *(const f16x8*)&As[( 0 + l15) * LDA + SWZ(l15, slot) * 8];
      const f16x8 a1 = *(const f16x8*)&As[(16 + l15) * LDA + SWZ(l15, slot) * 8];
      const f16x8 a2 = *(const f16x8*)&As[(32 + l15) * LDA + SWZ(l15, slot) * 8];
      const f16x8 a3 = *(const f16x8*)&As[(48 + l15) * LDA + SWZ(l15, slot) * 8];

#pragma unroll
      for (int ct = 0; ct < 4; ++ct) {
        acc[0][ct] = __builtin_amdgcn_mfma_f32_16x16x32_f16(a0, bb[cb][ct], acc[0][ct], 0, 0, 0);
        acc[1][ct] = __builtin_amdgcn_mfma_f32_16x16x32_f16(a1, bb[cb][ct], acc[1][ct], 0, 0, 0);
        acc[2][ct] = __builtin_amdgcn_mfma_f32_16x16x32_f16(a2, bb[cb][ct], acc[2][ct], 0, 0, 0);
        acc[3][ct] = __builtin_amdgcn_mfma_f32_16x16x32_f16(a3, bb[cb][ct], acc[3][ct], 0, 0, 0);
      }
    }

    // merge into per-(lane,slot) top-2 packed keys (score hi-bits | idx)
#pragma unroll
    for (int ct = 0; ct < 4; ++ct) {
      const uint idxv = (uint)(c4 * 256 + w4id * 64 + ct * 16 + l15);
#pragma unroll
      for (int rt = 0; rt < 4; ++rt)
#pragma unroll
        for (int r = 0; r < 4; ++r) {
          const float v = fmaxf(acc[rt][ct][r], 0.0f);
          const uint key = (__float_as_uint(v) & 0xFFFFFC00u) | idxv;
          const int slot = rt * 4 + r;
          t2[slot] = umed3(key, t1[slot], t2[slot]);
          t1[slot] = umax2(key, t1[slot]);
        }
    }
  }
#undef LOADB

  // ---- block-level per-row top-4 (reuse A LDS as key scratch: 64 rows x KSTR dwords) ----
  __syncthreads();   // all waves done with As
  uint* keys = (uint*)As;
#pragma unroll
  for (int slot = 0; slot < 16; ++slot) {
    const int rt = slot >> 2, r = slot & 3;
    const int row = rt * 16 + q * 4 + r;
    const int col = w4id * 32 + l15 * 2;
    keys[row * KSTR + col] = t1[slot];
    keys[row * KSTR + col + 1] = t2[slot];
  }
  __syncthreads();
  {
    const int row = t >> 2, seg = t & 3;   // 4 threads per row, 32 keys each
    uint s1 = 0, s2 = 0;
#pragma unroll
    for (int i = 0; i < 8; ++i) {
      const int ii = (i + t) & 7;
      const uint4 k4 = *(const uint4*)&keys[row * KSTR + seg * 32 + ii * 4];
      const uint kk[4] = {k4.x, k4.y, k4.z, k4.w};
#pragma unroll
      for (int e = 0; e < 4; ++e) {
        s2 = umed3(kk[e], s1, s2);
        s1 = umax2(kk[e], s1);
      }
    }
    __syncthreads();
    keys[t * 2] = s1;
    keys[t * 2 + 1] = s2;
  }
  __syncthreads();
  if (t < 64) {
    uint c0 = 0, c1 = 0, c2 = 0, c3 = 0;
#pragma unroll
    for (int i = 0; i < 8; ++i) {
      const uint k = keys[t * 8 + i];
      const uint n0 = umin2(c0, k); c0 = umax2(c0, k);
      const uint n1 = umin2(c1, n0); c1 = umax2(c1, n0);
      const uint n2 = umin2(c2, n1); c2 = umax2(c2, n1);
      c3 = umax2(c3, n2);
    }
    uint4 o; o.x = c0; o.y = c1; o.z = c2; o.w = c3;
    cand_s[t] = o;
  }
  __syncthreads();

  // ---- fp64 recheck: each thread covers its own (row, 64-d slice) with xv in regs ----
  double* red = (double*)As;   // 256 threads x 5 doubles = 10240 B
  {
    const uint4 ck = cand_s[r_own];
    const uint cv[4] = {ck.x, ck.y, ck.z, ck.w};
    double sxx_p = 0.0;
#pragma unroll
    for (int i = 0; i < 64; ++i) sxx_p = fma((double)xv[i], (double)xv[i], sxx_p);
#pragma unroll
    for (int j = 0; j < 4; ++j) {
      const int c = (int)(cv[j] & 1023u);
      const float* wr = w + (size_t)c * EMB_DIM + ph * 64;
      double s = 0.0;
#pragma unroll
      for (int k = 0; k < 16; ++k) {
        const float4 wv = *(const float4*)&wr[k * 4];
        s = fma((double)xv[k * 4 + 0], (double)wv.x, s);
        s = fma((double)xv[k * 4 + 1], (double)wv.y, s);
        s = fma((double)xv[k * 4 + 2], (double)wv.z, s);
        s = fma((double)xv[k * 4 + 3], (double)wv.w, s);
      }
      red[t * 5 + j] = s;
    }
    red[t * 5 + 4] = sxx_p;
  }
  __syncthreads();

  // ---- per-row decision (wave 0), loss reduce, idx store ----
  if (t < 64) {
    const uint4 ck = cand_s[t];
    const uint cv[4] = {ck.x, ck.y, ck.z, ck.w};
    double sj[4] = {0.0, 0.0, 0.0, 0.0};
    double sxx = 0.0;
#pragma unroll
    for (int p = 0; p < 4; ++p) {
      const int base = (p * 64 + t) * 5;
      sj[0] += red[base + 0];
      sj[1] += red[base + 1];
      sj[2] += red[base + 2];
      sj[3] += red[base + 3];
      sxx   += red[base + 4];
    }
    double qbest = -1e300; int cw = 1 << 30;
#pragma unroll
    for (int j = 0; j < 4; ++j) {
      const int c = (int)(cv[j] & 1023u);
      const double qj = sj[j] * rinv[c];
      if (qj > qbest || (qj == qbest && c < cw)) { qbest = qj; cw = c; }
    }
    const double dmin = 2.0 - 2.0 * qbest / fmax(sqrt(sxx), 1e-12);
    out[IDX_OFF + blk * 64 + t] = (float)cw;
    cw_s[t] = cw;
    double v = dmin;
    v += __shfl_down(v, 32);
    v += __shfl_down(v, 16);
    v += __shfl_down(v, 8);
    v += __shfl_down(v, 4);
    v += __shfl_down(v, 2);
    v += __shfl_down(v, 1);
    if (t == 0)
      atomicAdd(out, (float)(1.25 * v / 16777216.0));
  }
  __syncthreads();

  // ---- quant: two 32-row transpose passes through qs (reuses As) ----
  float* qs = (float*)As;   // [256 d][33] = 33792 B
  const int rw = t >> 3, li = t & 7;
#pragma unroll 1
  for (int half = 0; half < 2; ++half) {
    const int cw = cw_s[half * 32 + rw];
    const float* wr = wn + (size_t)cw * EMB_DIM;
#pragma unroll
    for (int k = 0; k < 8; ++k) {
      const int d0 = k * 32 + li * 4;
      const float4 wv = *(const float4*)&wr[d0];
      qs[(d0 + 0) * 33 + rw] = wv.x;
      qs[(d0 + 1) * 33 + rw] = wv.y;
      qs[(d0 + 2) * 33 + rw] = wv.z;
      qs[(d0 + 3) * 33 + rw] = wv.w;
    }
    __syncthreads();
    {
      const int hw4 = (t & 7) * 4, dbase = t >> 3;   // 32 d-groups of 8
      float* qout = out + QUANT_OFF + (size_t)b * (EMB_DIM * HW) + hw0 + half * 32;
#pragma unroll
      for (int jj = 0; jj < 8; ++jj) {
        const int d = jj * 32 + dbase;
        float4 v4;
        v4.x = qs[d * 33 + hw4 + 0];
        v4.y = qs[d * 33 + hw4 + 1];
        v4.z = qs[d * 33 + hw4 + 2];
        v4.w = qs[d * 33 + hw4 + 3];
        *(float4*)&qout[(size_t)d * HW + hw4] = v4;
      }
    }
    __syncthreads();
  }
}

extern "C" void kernel_launch(void* const* d_in, const int* in_sizes, int n_in,
                              void* d_out, int out_size, void* d_ws, size_t ws_size,
                              hipStream_t stream) {
  const float* x = (const float*)d_in[0];   // [64,256,32,32]
  const float* w = (const float*)d_in[1];   // [1024,256]
  float* out = (float*)d_out;               // [1 + 16777216 + 65536] f32

  char* ws = (char*)d_ws;
  float*     wn   = (float*)ws;                                // 1 MB
  _Float16*  wh2  = (_Float16*)(ws + 1048576);                 // 512 KB (swizzled)
  double*    rinv = (double*)(ws + 1048576 + 524288);          // 8 KB

  hipMemsetAsync(d_out, 0, sizeof(float), stream);   // zero loss accumulator
  hipLaunchKernelGGL(k_norm_w, dim3(NUM_EMB), dim3(256), 0, stream, w, wn, wh2, rinv);
  hipLaunchKernelGGL(k_fused, dim3(N_ROWS / 64), dim3(256), 0, stream, x, wh2, w, wn, rinv, out);
}

// Round 11
// 197.688 us; speedup vs baseline: 1.6258x; 1.4002x over previous
//
#include <hip/hip_runtime.h>
#include <math.h>

#define NUM_EMB 1024
#define EMB_DIM 256
#define N_ROWS  65536
#define HW      1024
#define QUANT_OFF 1
#define IDX_OFF   (1 + 16777216)
#define LDA 264   // halfs per A-row: 528B stride, affine addressing only (swizzle cost 30 regs, r10)
#define KSTR 132  // key-scratch row stride in dwords

typedef unsigned int uint;
typedef _Float16 f16x8 __attribute__((ext_vector_type(8)));
typedef float    f32x4 __attribute__((ext_vector_type(4)));

__device__ __forceinline__ uint umin2(uint a, uint b) { return a < b ? a : b; }
__device__ __forceinline__ uint umax2(uint a, uint b) { return a > b ? a : b; }

// median of 3 == 2nd-largest of 3; single VALU op on gfx9+
__device__ __forceinline__ uint umed3(uint a, uint b, uint c) {
  uint d;
  asm("v_med3_u32 %0, %1, %2, %3" : "=v"(d) : "v"(a), "v"(b), "v"(c));
  return d;
}

// ---- kernel 1: normalize codebook -> wn (f32), wh2 (f16, MFMA-B-swizzled), rinv (f64) ----
// wh2 halfs layout: [chunk(4)][ks(8)][q(4)][code-in-chunk(256)][e(8)], d = ks*32+q*8+e.
__global__ __launch_bounds__(256)
void k_norm_w(const float* __restrict__ w, float* __restrict__ wn,
              _Float16* __restrict__ wh2, double* __restrict__ rinv) {
  const int k = blockIdx.x, t = threadIdx.x;
  const float v = w[(size_t)k * EMB_DIM + t];
  double s = (double)v * (double)v;
  for (int o = 32; o; o >>= 1) s += __shfl_down(s, o);
  __shared__ double ps[4];
  if ((t & 63) == 0) ps[t >> 6] = s;
  __syncthreads();
  const double tot = ps[0] + ps[1] + ps[2] + ps[3];
  const float nv = v / fmaxf((float)sqrt(tot), 1e-12f);
  wn[(size_t)k * EMB_DIM + t] = nv;
  const int chunk = k >> 8, cc = k & 255;
  const int ks = t >> 5, q = (t >> 3) & 3, e = t & 7;
  wh2[(size_t)chunk * 65536 + ks * 8192 + q * 2048 + cc * 8 + e] = (_Float16)nv;
  if (t == 0) rinv[k] = 1.0 / fmax(sqrt(tot), 1e-12);
}

// ---- fused kernel: 64-row MFMA top-4 + chunked fp64 recheck + loss + quant ----
// 1024 blocks x 256 thr. GEMM phase = r3's proven loop (84 VGPR + 64 AGPR = 148,
// 3 waves/SIMD under (256,3)). NO xv held across phases (r4's xv cost a wave/SIMD);
// recheck re-reads x (L3) in 8-element chunks with IMMEDIATE consumption --
// r9's monolithic xf[64] burst needed 64 in-flight vaddr pairs and spilled.
__global__ __launch_bounds__(256, 3)
void k_fused(const float* __restrict__ x, const _Float16* __restrict__ wh2,
             const float* __restrict__ w, const float* __restrict__ wn,
             const double* __restrict__ rinv, float* __restrict__ out) {
  __shared__ __align__(16) _Float16 As[64 * LDA];   // 33792 B; reused: keys / red / qs
  __shared__ uint4 cand_s[64];
  __shared__ int   cw_s[64];
  const int t = threadIdx.x;
  const int blk = blockIdx.x;
  const int b = blk >> 4;
  const int hw0 = (blk & 15) * 64;

  const int lane = t & 63;
  const int q = lane >> 4;
  const int l15 = lane & 15;
  const int w4id = t >> 6;

  // per-lane B element offsets (halfs) within a ks-slab of wh2
  const int bvo0 = q * 2048 + (w4id * 64 +  0 + l15) * 8;
  const int bvo1 = q * 2048 + (w4id * 64 + 16 + l15) * 8;
  const int bvo2 = q * 2048 + (w4id * 64 + 32 + l15) * 8;
  const int bvo3 = q * 2048 + (w4id * 64 + 48 + l15) * 8;

#define LOADB(buf, cc, kk)                                            \
  { const _Float16* ksb_ = wh2 + (size_t)((cc) * 8 + (kk)) * 8192;    \
    buf[0] = *(const f16x8*)&ksb_[bvo0];                              \
    buf[1] = *(const f16x8*)&ksb_[bvo1];                              \
    buf[2] = *(const f16x8*)&ksb_[bvo2];                              \
    buf[3] = *(const f16x8*)&ksb_[bvo3]; }

  f16x8 bb[2][4];
  LOADB(bb[0], 0, 0);   // prefetch first B step (overlaps A staging)

  // stage A: x[b, d, hw0+r] f32 -> As[r][d] f16, packed 8 halfs per ds_write_b128
  const int r_own = t & 63;       // row this thread owns (staging, recheck, quant)
  const int ph = t >> 6;          // d-range: ph*64 .. ph*64+63
  {
    const float* xb = x + (size_t)b * (EMB_DIM * HW) + hw0 + r_own;
#pragma unroll
    for (int jp = 0; jp < 8; ++jp) {
      const int d0 = ph * 64 + jp * 8;
      f16x8 v;
#pragma unroll
      for (int e = 0; e < 8; ++e)
        v[e] = (_Float16)xb[(size_t)(d0 + e) * HW];
      *(f16x8*)&As[r_own * LDA + d0] = v;
    }
  }
  __syncthreads();   // A tile staged

  uint t1[16], t2[16];
#pragma unroll
  for (int i = 0; i < 16; ++i) { t1[i] = 0u; t2[i] = 0u; }

#pragma unroll
  for (int c4 = 0; c4 < 4; ++c4) {
    f32x4 acc[4][4];
#pragma unroll
    for (int rt = 0; rt < 4; ++rt)
#pragma unroll
      for (int ct = 0; ct < 4; ++ct) acc[rt][ct] = (f32x4)0.f;

#pragma unroll
    for (int ks = 0; ks < 8; ++ks) {
      const int s = c4 * 8 + ks;
      const int cb = s & 1, nb = cb ^ 1;  // static double-buffer indices
      if (s < 31) {
        const int sn = s + 1;
        LOADB(bb[nb], sn >> 3, sn & 7);
      }

      const f16x8 a0 = *(const f16x8*)&As[( 0 + l15) * LDA + ks * 32 + q * 8];
      const f16x8 a1 = *(const f16x8*)&As[(16 + l15) * LDA + ks * 32 + q * 8];
      const f16x8 a2 = *(const f16x8*)&As[(32 + l15) * LDA + ks * 32 + q * 8];
      const f16x8 a3 = *(const f16x8*)&As[(48 + l15) * LDA + ks * 32 + q * 8];

      __builtin_amdgcn_s_setprio(1);
#pragma unroll
      for (int ct = 0; ct < 4; ++ct) {
        acc[0][ct] = __builtin_amdgcn_mfma_f32_16x16x32_f16(a0, bb[cb][ct], acc[0][ct], 0, 0, 0);
        acc[1][ct] = __builtin_amdgcn_mfma_f32_16x16x32_f16(a1, bb[cb][ct], acc[1][ct], 0, 0, 0);
        acc[2][ct] = __builtin_amdgcn_mfma_f32_16x16x32_f16(a2, bb[cb][ct], acc[2][ct], 0, 0, 0);
        acc[3][ct] = __builtin_amdgcn_mfma_f32_16x16x32_f16(a3, bb[cb][ct], acc[3][ct], 0, 0, 0);
      }
      __builtin_amdgcn_s_setprio(0);
    }

    // merge into per-(lane,slot) top-2 packed keys (score hi-bits | idx)
#pragma unroll
    for (int ct = 0; ct < 4; ++ct) {
      const uint idxv = (uint)(c4 * 256 + w4id * 64 + ct * 16 + l15);
#pragma unroll
      for (int rt = 0; rt < 4; ++rt)
#pragma unroll
        for (int r = 0; r < 4; ++r) {
          const float v = fmaxf(acc[rt][ct][r], 0.0f);
          const uint key = (__float_as_uint(v) & 0xFFFFFC00u) | idxv;
          const int slot = rt * 4 + r;
          t2[slot] = umed3(key, t1[slot], t2[slot]);
          t1[slot] = umax2(key, t1[slot]);
        }
    }
  }
#undef LOADB

  // ---- block-level per-row top-4 (reuse A LDS as key scratch: 64 rows x KSTR dwords) ----
  __syncthreads();   // all waves done with As
  uint* keys = (uint*)As;
#pragma unroll
  for (int slot = 0; slot < 16; ++slot) {
    const int rt = slot >> 2, r = slot & 3;
    const int row = rt * 16 + q * 4 + r;
    const int col = w4id * 32 + l15 * 2;
    keys[row * KSTR + col] = t1[slot];
    keys[row * KSTR + col + 1] = t2[slot];
  }
  __syncthreads();
  {
    const int row = t >> 2, seg = t & 3;   // 4 threads per row, 32 keys each
    uint s1 = 0, s2 = 0;
#pragma unroll
    for (int i = 0; i < 8; ++i) {
      const int ii = (i + t) & 7;
      const uint4 k4 = *(const uint4*)&keys[row * KSTR + seg * 32 + ii * 4];
      const uint kk[4] = {k4.x, k4.y, k4.z, k4.w};
#pragma unroll
      for (int e = 0; e < 4; ++e) {
        s2 = umed3(kk[e], s1, s2);
        s1 = umax2(kk[e], s1);
      }
    }
    __syncthreads();
    keys[t * 2] = s1;
    keys[t * 2 + 1] = s2;
  }
  __syncthreads();
  if (t < 64) {
    uint c0 = 0, c1 = 0, c2 = 0, c3 = 0;
#pragma unroll
    for (int i = 0; i < 8; ++i) {
      const uint k = keys[t * 8 + i];
      const uint n0 = umin2(c0, k); c0 = umax2(c0, k);
      const uint n1 = umin2(c1, n0); c1 = umax2(c1, n0);
      const uint n2 = umin2(c2, n1); c2 = umax2(c2, n1);
      c3 = umax2(c3, n2);
    }
    uint4 o; o.x = c0; o.y = c1; o.z = c2; o.w = c3;
    cand_s[t] = o;
  }
  __syncthreads();

  // ---- fp64 recheck: chunked x re-read (L3), immediate consumption, low pressure ----
  double* red = (double*)As;   // 256 threads x 5 doubles = 10240 B
  {
    const uint4 ck = cand_s[r_own];
    const float* xr = x + (size_t)b * (EMB_DIM * HW) + hw0 + r_own;
    const float* w0 = w + (size_t)(ck.x & 1023u) * EMB_DIM + ph * 64;
    const float* w1 = w + (size_t)(ck.y & 1023u) * EMB_DIM + ph * 64;
    const float* w2 = w + (size_t)(ck.z & 1023u) * EMB_DIM + ph * 64;
    const float* w3 = w + (size_t)(ck.w & 1023u) * EMB_DIM + ph * 64;
    double sxx = 0.0, s0 = 0.0, s1 = 0.0, s2 = 0.0, s3 = 0.0;
#pragma unroll 1
    for (int cc = 0; cc < 8; ++cc) {
      float xf[8];
#pragma unroll
      for (int e = 0; e < 8; ++e)
        xf[e] = xr[(size_t)(ph * 64 + cc * 8 + e) * HW];
      const float4 a0 = *(const float4*)&w0[cc * 8];
      const float4 a1 = *(const float4*)&w0[cc * 8 + 4];
      const float4 b0 = *(const float4*)&w1[cc * 8];
      const float4 b1 = *(const float4*)&w1[cc * 8 + 4];
      const float4 c0 = *(const float4*)&w2[cc * 8];
      const float4 c1 = *(const float4*)&w2[cc * 8 + 4];
      const float4 d0 = *(const float4*)&w3[cc * 8];
      const float4 d1 = *(const float4*)&w3[cc * 8 + 4];
      const float wv0[8] = {a0.x, a0.y, a0.z, a0.w, a1.x, a1.y, a1.z, a1.w};
      const float wv1[8] = {b0.x, b0.y, b0.z, b0.w, b1.x, b1.y, b1.z, b1.w};
      const float wv2[8] = {c0.x, c0.y, c0.z, c0.w, c1.x, c1.y, c1.z, c1.w};
      const float wv3[8] = {d0.x, d0.y, d0.z, d0.w, d1.x, d1.y, d1.z, d1.w};
#pragma unroll
      for (int e = 0; e < 8; ++e) {
        const double xd = (double)xf[e];
        sxx = fma(xd, xd, sxx);
        s0 = fma(xd, (double)wv0[e], s0);
        s1 = fma(xd, (double)wv1[e], s1);
        s2 = fma(xd, (double)wv2[e], s2);
        s3 = fma(xd, (double)wv3[e], s3);
      }
    }
    red[t * 5 + 0] = s0;
    red[t * 5 + 1] = s1;
    red[t * 5 + 2] = s2;
    red[t * 5 + 3] = s3;
    red[t * 5 + 4] = sxx;
  }
  __syncthreads();

  // ---- per-row decision (wave 0), loss reduce, idx store ----
  if (t < 64) {
    const uint4 ck = cand_s[t];
    const uint cv[4] = {ck.x, ck.y, ck.z, ck.w};
    double sj[4] = {0.0, 0.0, 0.0, 0.0};
    double sxx = 0.0;
#pragma unroll
    for (int p = 0; p < 4; ++p) {
      const int base = (p * 64 + t) * 5;
      sj[0] += red[base + 0];
      sj[1] += red[base + 1];
      sj[2] += red[base + 2];
      sj[3] += red[base + 3];
      sxx   += red[base + 4];
    }
    double qbest = -1e300; int cw = 1 << 30;
#pragma unroll
    for (int j = 0; j < 4; ++j) {
      const int c = (int)(cv[j] & 1023u);
      const double qj = sj[j] * rinv[c];
      if (qj > qbest || (qj == qbest && c < cw)) { qbest = qj; cw = c; }
    }
    const double dmin = 2.0 - 2.0 * qbest / fmax(sqrt(sxx), 1e-12);
    out[IDX_OFF + blk * 64 + t] = (float)cw;
    cw_s[t] = cw;
    double v = dmin;
    v += __shfl_down(v, 32);
    v += __shfl_down(v, 16);
    v += __shfl_down(v, 8);
    v += __shfl_down(v, 4);
    v += __shfl_down(v, 2);
    v += __shfl_down(v, 1);
    if (t == 0)
      atomicAdd(out, (float)(1.25 * v / 16777216.0));
  }
  __syncthreads();

  // ---- quant: two 32-row transpose passes through qs (reuses As) ----
  float* qs = (float*)As;   // [256 d][33] = 33792 B
  const int rw = t >> 3, li = t & 7;
#pragma unroll 1
  for (int half = 0; half < 2; ++half) {
    const int cw = cw_s[half * 32 + rw];
    const float* wr = wn + (size_t)cw * EMB_DIM;
#pragma unroll
    for (int k = 0; k < 8; ++k) {
      const int d0 = k * 32 + li * 4;
      const float4 wv = *(const float4*)&wr[d0];
      qs[(d0 + 0) * 33 + rw] = wv.x;
      qs[(d0 + 1) * 33 + rw] = wv.y;
      qs[(d0 + 2) * 33 + rw] = wv.z;
      qs[(d0 + 3) * 33 + rw] = wv.w;
    }
    __syncthreads();
    {
      const int hw4 = (t & 7) * 4, dbase = t >> 3;   // 32 d-groups of 8
      float* qout = out + QUANT_OFF + (size_t)b * (EMB_DIM * HW) + hw0 + half * 32;
#pragma unroll
      for (int jj = 0; jj < 8; ++jj) {
        const int d = jj * 32 + dbase;
        float4 v4;
        v4.x = qs[d * 33 + hw4 + 0];
        v4.y = qs[d * 33 + hw4 + 1];
        v4.z = qs[d * 33 + hw4 + 2];
        v4.w = qs[d * 33 + hw4 + 3];
        *(float4*)&qout[(size_t)d * HW + hw4] = v4;
      }
    }
    __syncthreads();
  }
}

extern "C" void kernel_launch(void* const* d_in, const int* in_sizes, int n_in,
                              void* d_out, int out_size, void* d_ws, size_t ws_size,
                              hipStream_t stream) {
  const float* x = (const float*)d_in[0];   // [64,256,32,32]
  const float* w = (const float*)d_in[1];   // [1024,256]
  float* out = (float*)d_out;               // [1 + 16777216 + 65536] f32

  char* ws = (char*)d_ws;
  float*     wn   = (float*)ws;                                // 1 MB
  _Float16*  wh2  = (_Float16*)(ws + 1048576);                 // 512 KB (swizzled)
  double*    rinv = (double*)(ws + 1048576 + 524288);          // 8 KB

  hipMemsetAsync(d_out, 0, sizeof(float), stream);   // zero loss accumulator
  hipLaunchKernelGGL(k_norm_w, dim3(NUM_EMB), dim3(256), 0, stream, w, wn, wh2, rinv);
  hipLaunchKernelGGL(k_fused, dim3(N_ROWS / 64), dim3(256), 0, stream, x, wh2, w, wn, rinv, out);
}